// Round 2
// baseline (266.252 us; speedup 1.0000x reference)
//
#include <hip/hip_runtime.h>

#define INV_SQRT2 0.70710678118654752f
#define QSCALE    0.17677669529663689f   // 1/sqrt(HEAD_DIM=32)
#define LOG2E     1.44269504088896340f
#define SM_HALF   16.0f                  // softmax shift folded into acc init: s0,s1 each start at -16

typedef __attribute__((ext_vector_type(8))) short bf16x8;
typedef __attribute__((ext_vector_type(4))) float f32x4;
typedef __attribute__((ext_vector_type(16))) float f32x16;

// single-instruction packed f32->bf16 (RNE), dst.lo = bf16(a), dst.hi = bf16(b)
__device__ __forceinline__ unsigned cvt_pk_bf16(float a, float b) {
  unsigned r;
  asm("v_cvt_pk_bf16_f32 %0, %1, %2" : "=v"(r) : "v"(a), "v"(b));
  return r;
}

__device__ __forceinline__ float exp2_raw(float x) {
  float r;
  asm("v_exp_f32 %0, %1" : "=v"(r) : "v"(x));
  return r;
}

// async global->LDS, 16B per lane; LDS dest = wave-uniform base + lane*16
__device__ __forceinline__ void async16(const short* g, short* l) {
  typedef __attribute__((address_space(3))) unsigned lds_u32;
  typedef const __attribute__((address_space(1))) unsigned glb_u32;
  __builtin_amdgcn_global_load_lds((glb_u32*)g, (lds_u32*)l, 16, 0, 0);
}

// ---- fused pre-pass: DWT(q,k) + DWT(v)+transpose + iDWT-fused W_o, one launch ----
__launch_bounds__(256, 4)
__global__ void dwt_all(const float* __restrict__ q, const float* __restrict__ k,
                        const float* __restrict__ v, const float* __restrict__ W,
                        short* __restrict__ qs, short* __restrict__ ks,
                        short* __restrict__ vt, short* __restrict__ w2) {
  __shared__ float tL[32][65];
  __shared__ float tH[32][65];
  int bi = blockIdx.x;
  int t = threadIdx.x;
  if (bi < 2048) {
    int idx = bi * 256 + t;
    int j = idx & 31;
    int s = (idx >> 5) & 2047;
    int b = idx >> 16;
    const float4* qp = (const float4*)(q + ((size_t)(b * 2048 + s)) * 512 + j * 16);
    const float4* kp = (const float4*)(k + ((size_t)(b * 2048 + s)) * 512 + j * 16);
    float4 a0 = qp[0], a1 = qp[1], a2 = qp[2], a3 = qp[3];
    float4 c0 = kp[0], c1 = kp[1], c2 = kp[2], c3 = kp[3];
    union { bf16x8 v; unsigned u[4]; } qL, qH, kL, kH;
    const float cs = INV_SQRT2 * QSCALE * LOG2E;
    qL.u[0] = cvt_pk_bf16((a0.x + a0.y) * cs, (a0.z + a0.w) * cs);
    qL.u[1] = cvt_pk_bf16((a1.x + a1.y) * cs, (a1.z + a1.w) * cs);
    qL.u[2] = cvt_pk_bf16((a2.x + a2.y) * cs, (a2.z + a2.w) * cs);
    qL.u[3] = cvt_pk_bf16((a3.x + a3.y) * cs, (a3.z + a3.w) * cs);
    qH.u[0] = cvt_pk_bf16((a0.x - a0.y) * cs, (a0.z - a0.w) * cs);
    qH.u[1] = cvt_pk_bf16((a1.x - a1.y) * cs, (a1.z - a1.w) * cs);
    qH.u[2] = cvt_pk_bf16((a2.x - a2.y) * cs, (a2.z - a2.w) * cs);
    qH.u[3] = cvt_pk_bf16((a3.x - a3.y) * cs, (a3.z - a3.w) * cs);
    kL.u[0] = cvt_pk_bf16((c0.x + c0.y) * INV_SQRT2, (c0.z + c0.w) * INV_SQRT2);
    kL.u[1] = cvt_pk_bf16((c1.x + c1.y) * INV_SQRT2, (c1.z + c1.w) * INV_SQRT2);
    kL.u[2] = cvt_pk_bf16((c2.x + c2.y) * INV_SQRT2, (c2.z + c2.w) * INV_SQRT2);
    kL.u[3] = cvt_pk_bf16((c3.x + c3.y) * INV_SQRT2, (c3.z + c3.w) * INV_SQRT2);
    kH.u[0] = cvt_pk_bf16((c0.x - c0.y) * INV_SQRT2, (c0.z - c0.w) * INV_SQRT2);
    kH.u[1] = cvt_pk_bf16((c1.x - c1.y) * INV_SQRT2, (c1.z - c1.w) * INV_SQRT2);
    kH.u[2] = cvt_pk_bf16((c2.x - c2.y) * INV_SQRT2, (c2.z - c2.w) * INV_SQRT2);
    kH.u[3] = cvt_pk_bf16((c3.x - c3.y) * INV_SQRT2, (c3.z - c3.w) * INV_SQRT2);
    size_t oL = ((size_t)(b * 2) * 2048 + s) * 256 + j * 8;
    size_t oH = oL + (size_t)2048 * 256;
    *(bf16x8*)(qs + oL) = qL.v;  *(bf16x8*)(qs + oH) = qH.v;
    *(bf16x8*)(ks + oL) = kL.v;  *(bf16x8*)(ks + oH) = kH.v;
  } else if (bi < 4096) {
    int bi2 = bi - 2048;                 // [0,2048): 8 b x 64 st x 4 it
    int it = bi2 & 3, st = (bi2 >> 2) & 63, b = bi2 >> 8;
#pragma unroll
    for (int rep = 0; rep < 4; rep++) {
      int unit = rep * 256 + t;
      int r = unit >> 5, cp = (unit & 31) * 2;
      float4 vv = *(const float4*)(v + ((size_t)(b * 2048 + st * 32 + r)) * 512 + it * 128 + cp * 2);
      tL[r][cp]     = (vv.x + vv.y) * INV_SQRT2;
      tL[r][cp + 1] = (vv.z + vv.w) * INV_SQRT2;
      tH[r][cp]     = (vv.x - vv.y) * INV_SQRT2;
      tH[r][cp + 1] = (vv.z - vv.w) * INV_SQRT2;
    }
    __syncthreads();
    {
      int i = t >> 2, cc = t & 3;
      union { bf16x8 v; unsigned u[4]; } pL, pH;
#pragma unroll
      for (int p = 0; p < 4; p++) {
        pL.u[p] = cvt_pk_bf16(tL[cc * 8 + p * 2][i], tL[cc * 8 + p * 2 + 1][i]);
        pH.u[p] = cvt_pk_bf16(tH[cc * 8 + p * 2][i], tH[cc * 8 + p * 2 + 1][i]);
      }
      size_t o = ((size_t)(b * 2) * 256 + it * 64 + i) * 2048 + st * 32 + cc * 8;
      *(bf16x8*)(vt + o) = pL.v;
      *(bf16x8*)(vt + o + (size_t)256 * 2048) = pH.v;
    }
  } else {
    int idx = (bi - 4096) * 256 + t;
    int j = idx >> 6, i4 = (idx & 63) * 4;
    const float4* src = (const float4*)(W + (size_t)j * 512 + 2 * i4);
    float4 f0 = src[0], f1 = src[1];
    uint2 dl, dh;
    dl.x = cvt_pk_bf16((f0.x + f0.y) * INV_SQRT2, (f0.z + f0.w) * INV_SQRT2);
    dl.y = cvt_pk_bf16((f1.x + f1.y) * INV_SQRT2, (f1.z + f1.w) * INV_SQRT2);
    dh.x = cvt_pk_bf16((f0.x - f0.y) * INV_SQRT2, (f0.z - f0.w) * INV_SQRT2);
    dh.y = cvt_pk_bf16((f1.x - f1.y) * INV_SQRT2, (f1.z - f1.w) * INV_SQRT2);
    *(uint2*)(w2 + (size_t)j * 512 + i4) = dl;
    *(uint2*)(w2 + (size_t)j * 512 + 256 + i4) = dh;
  }
}

// ---- flash attention: V^T direct-from-L2 (no V LDS), counted b1 barrier ----
// S: wave (ct,qt) computes kv32 x q32. PV: wave w computes d[w*64..+64) x q64.
// LDS (shorts): K [0,16384) | P [16384,20480)  -> 40KB total
__launch_bounds__(256, 2)
__global__ void flash_attn(const short* __restrict__ qs, const short* __restrict__ ks,
                           const short* __restrict__ vt, short* __restrict__ os) {
  __shared__ short lds[20480];
  short* klds = lds;
  short* plds = lds + 16384;

  int tid = threadIdx.x;
  int w = tid >> 6, L = tid & 63;
  int lq = L & 31, hi = L >> 5;
  int qt = w & 1, ct = w >> 1;
  int bb = blockIdx.x, qb = blockIdx.y;  // bb fastest -> XCD L2 locality on K/V

  // Q as B-operand fragments: B[k = hi*8+j][n = lq]
  bf16x8 qf[16];
  const short* qptr = qs + (((size_t)bb * 2048) + qb * 64 + qt * 32 + lq) * 256 + hi * 8;
#pragma unroll
  for (int ksI = 0; ksI < 16; ksI++)
    qf[ksI] = *(const bf16x8*)(qptr + ksI * 16);

  f32x16 oacc[4];   // [dt*2+qt2]: d = w*64+dt*32+rows, q = qt2*32+lq
#pragma unroll
  for (int mt = 0; mt < 4; mt++)
#pragma unroll
    for (int i = 0; i < 16; i++) oacc[mt][i] = 0.f;
  float l_i = 0.f;

  const short* kbase = ks + ((size_t)bb * 2048) * 256;
  const short* vbase = vt + ((size_t)bb * 256) * 2048;

  int krow = ct * 32 + lq, ksw = krow & 7;
  int qrow = qt * 32 + lq, qsw = qrow & 7;
  int sw8 = lq & 7;

  // ---- hoisted loop-invariant LDS addresses ----
  const short* kaddr[16];
#pragma unroll
  for (int i = 0; i < 16; i++)
    kaddr[i] = klds + krow * 256 + (((i << 1) | hi) ^ ksw) * 8;
  short* pwr[4];
#pragma unroll
  for (int g = 0; g < 4; g++)
    pwr[g] = plds + qrow * 64 + ((4 * ct + g) ^ qsw) * 8 + hi * 4;
  const short* prdA[4];   // P reads for q-half 0 (rows lq)
  const short* prdB[4];   // q-half 1 (rows 32+lq)
#pragma unroll
  for (int i = 0; i < 4; i++) {
    int ch = (((i << 1) | hi) ^ sw8) * 8;
    prdA[i] = plds + lq * 64 + ch;
    prdB[i] = plds + (32 + lq) * 64 + ch;
  }

  // ---- V^T direct-global fragment bases (unswizzled vt layout) ----
  // lane reads V^T[d][kt*64 + i*16 + hi*8 .. +8): 16B dwordx4, i*32B immediate offsets
  const short* vga = vbase + (size_t)(w * 64 + lq) * 2048 + hi * 8;        // dt=0 rows
  const short* vgb = vga + (size_t)32 * 2048;                              // dt=1 rows

  // ---- hoisted K DMA source pointers ----
  const short* kp[8];
#pragma unroll
  for (int rep = 0; rep < 8; rep++) {
    int o = w * 8 + rep;
    int r = 2 * o + (L >> 5);
    int c = (L & 31) ^ (r & 7);
    kp[rep] = kbase + r * 256 + c * 8;
  }

  // prologue: stage K[0]
#pragma unroll
  for (int rep = 0; rep < 8; rep++) {
    async16(kp[rep], klds + (w * 8 + rep) * 512);
    kp[rep] += 16384;
  }
  __syncthreads();

  for (int kt = 0; kt < 32; kt++) {
    // ---- S^T tile: two interleaved accumulator chains; softmax shift pre-folded ----
    f32x16 s0, s1;
#pragma unroll
    for (int i = 0; i < 16; i++) { s0[i] = -SM_HALF; s1[i] = -SM_HALF; }
    __builtin_amdgcn_s_setprio(1);
#pragma unroll
    for (int ksI = 0; ksI < 16; ksI += 2) {
      bf16x8 kb0 = *(const bf16x8*)kaddr[ksI];
      bf16x8 kb1 = *(const bf16x8*)kaddr[ksI + 1];
      s0 = __builtin_amdgcn_mfma_f32_32x32x16_bf16(kb0, qf[ksI], s0, 0, 0, 0);
      s1 = __builtin_amdgcn_mfma_f32_32x32x16_bf16(kb1, qf[ksI + 1], s1, 0, 0, 0);
    }
    __builtin_amdgcn_s_setprio(0);

    // ---- softmax numerator + P write + partial l ----
    float rs = 0.f;
#pragma unroll
    for (int g = 0; g < 4; g++) {
      float p0 = exp2_raw(s0[4 * g]     + s1[4 * g]);
      float p1 = exp2_raw(s0[4 * g + 1] + s1[4 * g + 1]);
      float p2 = exp2_raw(s0[4 * g + 2] + s1[4 * g + 2]);
      float p3 = exp2_raw(s0[4 * g + 3] + s1[4 * g + 3]);
      rs += (p0 + p1) + (p2 + p3);
      uint2 d; d.x = cvt_pk_bf16(p0, p1); d.y = cvt_pk_bf16(p2, p3);
      *(uint2*)pwr[g] = d;
    }
    l_i += rs;

    // ---- V[kt] global loads: issued BEFORE b1, stay in flight across it ----
    bf16x8 va0 = *(const bf16x8*)(vga + 0);
    bf16x8 va1 = *(const bf16x8*)(vga + 16);
    bf16x8 va2 = *(const bf16x8*)(vga + 32);
    bf16x8 va3 = *(const bf16x8*)(vga + 48);
    bf16x8 vB0 = *(const bf16x8*)(vgb + 0);
    bf16x8 vB1 = *(const bf16x8*)(vgb + 16);
    bf16x8 vB2 = *(const bf16x8*)(vgb + 32);
    bf16x8 vB3 = *(const bf16x8*)(vgb + 48);
    vga += 64; vgb += 64;

    // b1 (counted): P ds_writes visible + K ds_reads retired; no vmcnt drain
    asm volatile("s_waitcnt lgkmcnt(0)" ::: "memory");
    __builtin_amdgcn_s_barrier();

    // K[kt+1] DMA; drains at b2 behind PV
    if (kt < 31) {
#pragma unroll
      for (int rep = 0; rep < 8; rep++) {
        async16(kp[rep], klds + (w * 8 + rep) * 512);
        kp[rep] += 16384;
      }
    }

    // ---- O^T += V^T P^T ----
    bf16x8 pa[4], pb[4];
#pragma unroll
    for (int i = 0; i < 4; i++) {
      pa[i] = *(const bf16x8*)prdA[i];
      pb[i] = *(const bf16x8*)prdB[i];
    }
    __builtin_amdgcn_s_setprio(1);
    oacc[0] = __builtin_amdgcn_mfma_f32_32x32x16_bf16(va0, pa[0], oacc[0], 0, 0, 0);
    oacc[1] = __builtin_amdgcn_mfma_f32_32x32x16_bf16(va0, pb[0], oacc[1], 0, 0, 0);
    oacc[0] = __builtin_amdgcn_mfma_f32_32x32x16_bf16(va1, pa[1], oacc[0], 0, 0, 0);
    oacc[1] = __builtin_amdgcn_mfma_f32_32x32x16_bf16(va1, pb[1], oacc[1], 0, 0, 0);
    oacc[0] = __builtin_amdgcn_mfma_f32_32x32x16_bf16(va2, pa[2], oacc[0], 0, 0, 0);
    oacc[1] = __builtin_amdgcn_mfma_f32_32x32x16_bf16(va2, pb[2], oacc[1], 0, 0, 0);
    oacc[0] = __builtin_amdgcn_mfma_f32_32x32x16_bf16(va3, pa[3], oacc[0], 0, 0, 0);
    oacc[1] = __builtin_amdgcn_mfma_f32_32x32x16_bf16(va3, pb[3], oacc[1], 0, 0, 0);
    oacc[2] = __builtin_amdgcn_mfma_f32_32x32x16_bf16(vB0, pa[0], oacc[2], 0, 0, 0);
    oacc[3] = __builtin_amdgcn_mfma_f32_32x32x16_bf16(vB0, pb[0], oacc[3], 0, 0, 0);
    oacc[2] = __builtin_amdgcn_mfma_f32_32x32x16_bf16(vB1, pa[1], oacc[2], 0, 0, 0);
    oacc[3] = __builtin_amdgcn_mfma_f32_32x32x16_bf16(vB1, pb[1], oacc[3], 0, 0, 0);
    oacc[2] = __builtin_amdgcn_mfma_f32_32x32x16_bf16(vB2, pa[2], oacc[2], 0, 0, 0);
    oacc[3] = __builtin_amdgcn_mfma_f32_32x32x16_bf16(vB2, pb[2], oacc[3], 0, 0, 0);
    oacc[2] = __builtin_amdgcn_mfma_f32_32x32x16_bf16(vB3, pa[3], oacc[2], 0, 0, 0);
    oacc[3] = __builtin_amdgcn_mfma_f32_32x32x16_bf16(vB3, pb[3], oacc[3], 0, 0, 0);
    __builtin_amdgcn_s_setprio(0);
    __syncthreads();   // b2: P reads retired; K[kt+1] DMA drained
  }

  // ---- epilogue: merge l, normalize, transpose via LDS, store ----
  float lt = l_i + __shfl_xor(l_i, 32, 64);
  float* lbuf = (float*)(lds + 20224);   // disjoint from transpose region [0,16896)
  if (hi == 0) lbuf[(ct * 2 + qt) * 32 + lq] = lt;
  __syncthreads();
  float inv0 = 1.f / (lbuf[lq] + lbuf[64 + lq]);
  float inv1 = 1.f / (lbuf[32 + lq] + lbuf[96 + lq]);

#pragma unroll
  for (int ot = 0; ot < 4; ot++) {
    int qt2 = ot & 1, dt = ot >> 1;
    float inv = qt2 ? inv1 : inv0;
    int qg = qt2 * 32 + lq;
#pragma unroll
    for (int g = 0; g < 4; g++) {
      uint2 d;
      d.x = cvt_pk_bf16(oacc[ot][4 * g] * inv, oacc[ot][4 * g + 1] * inv);
      d.y = cvt_pk_bf16(oacc[ot][4 * g + 2] * inv, oacc[ot][4 * g + 3] * inv);
      *(uint2*)(lds + qg * 264 + w * 64 + dt * 32 + 8 * g + 4 * hi) = d;
    }
  }
  __syncthreads();
  short* obase = os + (((size_t)bb * 2048) + qb * 64) * 256;
#pragma unroll
  for (int rep = 0; rep < 8; rep++) {
    int cid = rep * 256 + tid;
    int row = cid >> 5, c = cid & 31;
    *(bf16x8*)(obase + row * 256 + c * 8) = *(const bf16x8*)(lds + row * 264 + c * 8);
  }
}

// ---- out = [O_L|O_H] @ w2^T + b_o : 128x128 tiles, BK=64, async-DMA double-buffered ----
__launch_bounds__(256, 2)
__global__ void out_gemm(const short* __restrict__ os, const short* __restrict__ w2,
                         const float* __restrict__ bo, float* __restrict__ out) {
  __shared__ short alds[2][8192];   // 128 rows x 64 k (xor-chunk swizzled)
  __shared__ short blds[2][8192];
  int tid = threadIdx.x;
  int w = tid >> 6, L = tid & 63, lo = L & 15, hi = L >> 4;
  int wr = w >> 1, wc = w & 1;
  int br = blockIdx.x, bc = blockIdx.y;

  // DMA lane geometry: op o = w*4+rep covers rows o*8..o*8+7, lane chunk L&7
  int rrow[4], rchk[4];
#pragma unroll
  for (int rep = 0; rep < 4; rep++) {
    int o = w * 4 + rep;
    int r = o * 8 + (L >> 3);
    rrow[rep] = r;
    rchk[rep] = ((L & 7) ^ (r & 7)) * 8;
  }
  int b = br >> 4;
  int s0 = (br & 15) * 128;
  const short* abase = os + ((size_t)(b * 2) * 2048 + s0) * 256;   // + half*2048*256 + row*256 + i0 + chk
  const short* bbase = w2 + (size_t)(bc * 128) * 512;              // + row*512 + kt*64 + chk

  f32x4 acc[4][4];
#pragma unroll
  for (int mt = 0; mt < 4; mt++)
#pragma unroll
    for (int nt = 0; nt < 4; nt++)
      acc[mt][nt] = (f32x4){0.f, 0.f, 0.f, 0.f};

  // frag read offsets (swizzle reduces to lo&7; rows multiple-of-16 apart)
  int fch[2];
#pragma unroll
  for (int kc = 0; kc < 2; kc++)
    fch[kc] = ((kc * 4 + hi) ^ (lo & 7)) * 8;

  // prologue: stage kt=0 into buf 0
#pragma unroll
  for (int rep = 0; rep < 4; rep++) {
    async16(abase + rrow[rep] * 256 + rchk[rep], &alds[0][(w * 4 + rep) * 512] + L * 8);
    async16(bbase + rrow[rep] * 512 + rchk[rep], &blds[0][(w * 4 + rep) * 512] + L * 8);
  }
  __syncthreads();

  int p = 0;
  for (int kt = 0; kt < 8; kt++) {
    if (kt < 7) {
      int k1 = kt + 1;
      int half = k1 >> 2, i0 = (k1 & 3) * 64;
      const short* ab = abase + (size_t)half * 2048 * 256 + i0;
#pragma unroll
      for (int rep = 0; rep < 4; rep++) {
        async16(ab + rrow[rep] * 256 + rchk[rep], &alds[p ^ 1][(w * 4 + rep) * 512] + L * 8);
        async16(bbase + rrow[rep] * 512 + k1 * 64 + rchk[rep], &blds[p ^ 1][(w * 4 + rep) * 512] + L * 8);
      }
    }
    bf16x8 af[4], bfr[4];
#pragma unroll
    for (int kc = 0; kc < 2; kc++) {
#pragma unroll
      for (int mt = 0; mt < 4; mt++)
        af[mt] = *(const bf16x8*)(&alds[p][(wr * 64 + mt * 16 + lo) * 64 + fch[kc]]);
#pragma unroll
      for (int nt = 0; nt < 4; nt++)
        bfr[nt] = *(const bf16x8*)(&blds[p][(wc * 64 + nt * 16 + lo) * 64 + fch[kc]]);
#pragma unroll
      for (int mt = 0; mt < 4; mt++)
#pragma unroll
        for (int nt = 0; nt < 4; nt++)
          acc[mt][nt] = __builtin_amdgcn_mfma_f32_16x16x32_bf16(af[mt], bfr[nt], acc[mt][nt], 0, 0, 0);
    }
    __syncthreads();   // reads of buf p done; DMA into p^1 drained
    p ^= 1;
  }

#pragma unroll
  for (int nt = 0; nt < 4; nt++) {
    int cc = bc * 128 + wc * 64 + nt * 16 + lo;
    float bias = bo[cc];
#pragma unroll
    for (int mt = 0; mt < 4; mt++) {
      int rrbase = br * 128 + wr * 64 + mt * 16 + hi * 4;
#pragma unroll
      for (int r = 0; r < 4; r++)
        out[(size_t)(rrbase + r) * 512 + cc] = acc[mt][nt][r] + bias;
    }
  }
}

extern "C" void kernel_launch(void* const* d_in, const int* in_sizes, int n_in,
                              void* d_out, int out_size, void* d_ws, size_t ws_size,
                              hipStream_t stream) {
  const float* q  = (const float*)d_in[0];
  const float* k  = (const float*)d_in[1];
  const float* v  = (const float*)d_in[2];
  const float* W  = (const float*)d_in[3];
  const float* bo = (const float*)d_in[4];
  short* ws  = (short*)d_ws;
  short* qs  = ws;
  short* ksb = ws + (size_t)8  * 1024 * 1024;
  short* vtp = ws + (size_t)16 * 1024 * 1024;
  short* osb = ws + (size_t)24 * 1024 * 1024;
  short* w2  = ws + (size_t)32 * 1024 * 1024;   // 512x512 bf16

  dwt_all<<<4224, 256, 0, stream>>>(q, k, v, W, qs, ksb, vtp, w2);
  flash_attn<<<dim3(16, 32), 256, 0, stream>>>(qs, ksb, vtp, osb);
  out_gemm<<<dim3(128, 4), 256, 0, stream>>>(osb, w2, bo, (float*)d_out);
}

// Round 3
// 252.520 us; speedup vs baseline: 1.0544x; 1.0544x over previous
//
#include <hip/hip_runtime.h>

#define INV_SQRT2 0.70710678118654752f
#define QSCALE    0.17677669529663689f   // 1/sqrt(HEAD_DIM=32)
#define LOG2E     1.44269504088896340f
#define SM_HALF   16.0f                  // softmax shift folded into acc init: s0,s1 each start at -16

typedef __attribute__((ext_vector_type(8))) short bf16x8;
typedef __attribute__((ext_vector_type(4))) float f32x4;
typedef __attribute__((ext_vector_type(16))) float f32x16;

// single-instruction packed f32->bf16 (RNE), dst.lo = bf16(a), dst.hi = bf16(b)
__device__ __forceinline__ unsigned cvt_pk_bf16(float a, float b) {
  unsigned r;
  asm("v_cvt_pk_bf16_f32 %0, %1, %2" : "=v"(r) : "v"(a), "v"(b));
  return r;
}

__device__ __forceinline__ float exp2_raw(float x) {
  float r;
  asm("v_exp_f32 %0, %1" : "=v"(r) : "v"(x));
  return r;
}

// async global->LDS, 16B per lane; LDS dest = wave-uniform base + lane*16
__device__ __forceinline__ void async16(const short* g, short* l) {
  typedef __attribute__((address_space(3))) unsigned lds_u32;
  typedef const __attribute__((address_space(1))) unsigned glb_u32;
  __builtin_amdgcn_global_load_lds((glb_u32*)g, (lds_u32*)l, 16, 0, 0);
}

// ---- fused pre-pass: DWT(q,k) + DWT(v)+transpose + iDWT-fused W_o, one launch ----
__launch_bounds__(256, 4)
__global__ void dwt_all(const float* __restrict__ q, const float* __restrict__ k,
                        const float* __restrict__ v, const float* __restrict__ W,
                        short* __restrict__ qs, short* __restrict__ ks,
                        short* __restrict__ vt, short* __restrict__ w2) {
  __shared__ float tL[32][65];
  __shared__ float tH[32][65];
  int bi = blockIdx.x;
  int t = threadIdx.x;
  if (bi < 2048) {
    int idx = bi * 256 + t;
    int j = idx & 31;
    int s = (idx >> 5) & 2047;
    int b = idx >> 16;
    const float4* qp = (const float4*)(q + ((size_t)(b * 2048 + s)) * 512 + j * 16);
    const float4* kp = (const float4*)(k + ((size_t)(b * 2048 + s)) * 512 + j * 16);
    float4 a0 = qp[0], a1 = qp[1], a2 = qp[2], a3 = qp[3];
    float4 c0 = kp[0], c1 = kp[1], c2 = kp[2], c3 = kp[3];
    union { bf16x8 v; unsigned u[4]; } qL, qH, kL, kH;
    const float cs = INV_SQRT2 * QSCALE * LOG2E;
    qL.u[0] = cvt_pk_bf16((a0.x + a0.y) * cs, (a0.z + a0.w) * cs);
    qL.u[1] = cvt_pk_bf16((a1.x + a1.y) * cs, (a1.z + a1.w) * cs);
    qL.u[2] = cvt_pk_bf16((a2.x + a2.y) * cs, (a2.z + a2.w) * cs);
    qL.u[3] = cvt_pk_bf16((a3.x + a3.y) * cs, (a3.z + a3.w) * cs);
    qH.u[0] = cvt_pk_bf16((a0.x - a0.y) * cs, (a0.z - a0.w) * cs);
    qH.u[1] = cvt_pk_bf16((a1.x - a1.y) * cs, (a1.z - a1.w) * cs);
    qH.u[2] = cvt_pk_bf16((a2.x - a2.y) * cs, (a2.z - a2.w) * cs);
    qH.u[3] = cvt_pk_bf16((a3.x - a3.y) * cs, (a3.z - a3.w) * cs);
    kL.u[0] = cvt_pk_bf16((c0.x + c0.y) * INV_SQRT2, (c0.z + c0.w) * INV_SQRT2);
    kL.u[1] = cvt_pk_bf16((c1.x + c1.y) * INV_SQRT2, (c1.z + c1.w) * INV_SQRT2);
    kL.u[2] = cvt_pk_bf16((c2.x + c2.y) * INV_SQRT2, (c2.z + c2.w) * INV_SQRT2);
    kL.u[3] = cvt_pk_bf16((c3.x + c3.y) * INV_SQRT2, (c3.z + c3.w) * INV_SQRT2);
    kH.u[0] = cvt_pk_bf16((c0.x - c0.y) * INV_SQRT2, (c0.z - c0.w) * INV_SQRT2);
    kH.u[1] = cvt_pk_bf16((c1.x - c1.y) * INV_SQRT2, (c1.z - c1.w) * INV_SQRT2);
    kH.u[2] = cvt_pk_bf16((c2.x - c2.y) * INV_SQRT2, (c2.z - c2.w) * INV_SQRT2);
    kH.u[3] = cvt_pk_bf16((c3.x - c3.y) * INV_SQRT2, (c3.z - c3.w) * INV_SQRT2);
    size_t oL = ((size_t)(b * 2) * 2048 + s) * 256 + j * 8;
    size_t oH = oL + (size_t)2048 * 256;
    *(bf16x8*)(qs + oL) = qL.v;  *(bf16x8*)(qs + oH) = qH.v;
    *(bf16x8*)(ks + oL) = kL.v;  *(bf16x8*)(ks + oH) = kH.v;
  } else if (bi < 4096) {
    int bi2 = bi - 2048;                 // [0,2048): 8 b x 64 st x 4 it
    int it = bi2 & 3, st = (bi2 >> 2) & 63, b = bi2 >> 8;
#pragma unroll
    for (int rep = 0; rep < 4; rep++) {
      int unit = rep * 256 + t;
      int r = unit >> 5, cp = (unit & 31) * 2;
      float4 vv = *(const float4*)(v + ((size_t)(b * 2048 + st * 32 + r)) * 512 + it * 128 + cp * 2);
      tL[r][cp]     = (vv.x + vv.y) * INV_SQRT2;
      tL[r][cp + 1] = (vv.z + vv.w) * INV_SQRT2;
      tH[r][cp]     = (vv.x - vv.y) * INV_SQRT2;
      tH[r][cp + 1] = (vv.z - vv.w) * INV_SQRT2;
    }
    __syncthreads();
    {
      int i = t >> 2, cc = t & 3;
      union { bf16x8 v; unsigned u[4]; } pL, pH;
#pragma unroll
      for (int p = 0; p < 4; p++) {
        pL.u[p] = cvt_pk_bf16(tL[cc * 8 + p * 2][i], tL[cc * 8 + p * 2 + 1][i]);
        pH.u[p] = cvt_pk_bf16(tH[cc * 8 + p * 2][i], tH[cc * 8 + p * 2 + 1][i]);
      }
      size_t o = ((size_t)(b * 2) * 256 + it * 64 + i) * 2048 + st * 32 + cc * 8;
      *(bf16x8*)(vt + o) = pL.v;
      *(bf16x8*)(vt + o + (size_t)256 * 2048) = pH.v;
    }
  } else {
    int idx = (bi - 4096) * 256 + t;
    int j = idx >> 6, i4 = (idx & 63) * 4;
    const float4* src = (const float4*)(W + (size_t)j * 512 + 2 * i4);
    float4 f0 = src[0], f1 = src[1];
    uint2 dl, dh;
    dl.x = cvt_pk_bf16((f0.x + f0.y) * INV_SQRT2, (f0.z + f0.w) * INV_SQRT2);
    dl.y = cvt_pk_bf16((f1.x + f1.y) * INV_SQRT2, (f1.z + f1.w) * INV_SQRT2);
    dh.x = cvt_pk_bf16((f0.x - f0.y) * INV_SQRT2, (f0.z - f0.w) * INV_SQRT2);
    dh.y = cvt_pk_bf16((f1.x - f1.y) * INV_SQRT2, (f1.z - f1.w) * INV_SQRT2);
    *(uint2*)(w2 + (size_t)j * 512 + i4) = dl;
    *(uint2*)(w2 + (size_t)j * 512 + 256 + i4) = dh;
  }
}

// ---- flash attention: V^T direct-from-L2, loads HOISTED for latency cover ----
// S: wave (ct,qt) computes kv32 x q32. PV: wave w computes d[w*64..+64) x q64.
// LDS (shorts): K [0,16384) | P [16384,20480)  -> 40KB total
__launch_bounds__(256, 2)
__global__ void flash_attn(const short* __restrict__ qs, const short* __restrict__ ks,
                           const short* __restrict__ vt, short* __restrict__ os) {
  __shared__ short lds[20480];
  short* klds = lds;
  short* plds = lds + 16384;

  int tid = threadIdx.x;
  int w = tid >> 6, L = tid & 63;
  int lq = L & 31, hi = L >> 5;
  int qt = w & 1, ct = w >> 1;
  int bb = blockIdx.x, qb = blockIdx.y;  // bb fastest -> XCD L2 locality on K/V

  // Q as B-operand fragments: B[k = hi*8+j][n = lq]
  bf16x8 qf[16];
  const short* qptr = qs + (((size_t)bb * 2048) + qb * 64 + qt * 32 + lq) * 256 + hi * 8;
#pragma unroll
  for (int ksI = 0; ksI < 16; ksI++)
    qf[ksI] = *(const bf16x8*)(qptr + ksI * 16);

  f32x16 oacc[4];   // [dt*2+qt2]: d = w*64+dt*32+rows, q = qt2*32+lq
#pragma unroll
  for (int mt = 0; mt < 4; mt++)
#pragma unroll
    for (int i = 0; i < 16; i++) oacc[mt][i] = 0.f;
  float l_i = 0.f;

  const short* kbase = ks + ((size_t)bb * 2048) * 256;
  const short* vbase = vt + ((size_t)bb * 256) * 2048;

  int krow = ct * 32 + lq, ksw = krow & 7;
  int qrow = qt * 32 + lq, qsw = qrow & 7;
  int sw8 = lq & 7;

  // ---- hoisted loop-invariant LDS addresses ----
  const short* kaddr[16];
#pragma unroll
  for (int i = 0; i < 16; i++)
    kaddr[i] = klds + krow * 256 + (((i << 1) | hi) ^ ksw) * 8;
  short* pwr[4];
#pragma unroll
  for (int g = 0; g < 4; g++)
    pwr[g] = plds + qrow * 64 + ((4 * ct + g) ^ qsw) * 8 + hi * 4;
  const short* prdA[4];   // P reads for q-half 0 (rows lq)
  const short* prdB[4];   // q-half 1 (rows 32+lq)
#pragma unroll
  for (int i = 0; i < 4; i++) {
    int ch = (((i << 1) | hi) ^ sw8) * 8;
    prdA[i] = plds + lq * 64 + ch;
    prdB[i] = plds + (32 + lq) * 64 + ch;
  }

  // ---- V^T direct-global fragment bases (unswizzled vt layout) ----
  const short* vga = vbase + (size_t)(w * 64 + lq) * 2048 + hi * 8;        // dt=0 rows
  const short* vgb = vga + (size_t)32 * 2048;                              // dt=1 rows

  // ---- hoisted K DMA source pointers ----
  const short* kp[8];
#pragma unroll
  for (int rep = 0; rep < 8; rep++) {
    int o = w * 8 + rep;
    int r = 2 * o + (L >> 5);
    int c = (L & 31) ^ (r & 7);
    kp[rep] = kbase + r * 256 + c * 8;
  }

  // prologue: stage K[0]
#pragma unroll
  for (int rep = 0; rep < 8; rep++) {
    async16(kp[rep], klds + (w * 8 + rep) * 512);
    kp[rep] += 16384;
  }
  __syncthreads();

  for (int kt = 0; kt < 32; kt++) {
    // ---- V[kt] dt=0 loads at TOP: covered by full S-chain + softmax + barrier ----
    bf16x8 va0 = *(const bf16x8*)(vga + 0);
    bf16x8 va1 = *(const bf16x8*)(vga + 16);
    bf16x8 va2 = *(const bf16x8*)(vga + 32);
    bf16x8 va3 = *(const bf16x8*)(vga + 48);
    vga += 64;

    // ---- S^T tile: two interleaved accumulator chains; softmax shift pre-folded ----
    f32x16 s0, s1;
#pragma unroll
    for (int i = 0; i < 16; i++) { s0[i] = -SM_HALF; s1[i] = -SM_HALF; }
    __builtin_amdgcn_s_setprio(1);
#pragma unroll
    for (int ksI = 0; ksI < 16; ksI += 2) {
      bf16x8 kb0 = *(const bf16x8*)kaddr[ksI];
      bf16x8 kb1 = *(const bf16x8*)kaddr[ksI + 1];
      s0 = __builtin_amdgcn_mfma_f32_32x32x16_bf16(kb0, qf[ksI], s0, 0, 0, 0);
      s1 = __builtin_amdgcn_mfma_f32_32x32x16_bf16(kb1, qf[ksI + 1], s1, 0, 0, 0);
    }
    __builtin_amdgcn_s_setprio(0);

    // ---- V[kt] dt=1 loads: covered by softmax + barrier + K-DMA + P reads + 8 MFMA ----
    bf16x8 vB0 = *(const bf16x8*)(vgb + 0);
    bf16x8 vB1 = *(const bf16x8*)(vgb + 16);
    bf16x8 vB2 = *(const bf16x8*)(vgb + 32);
    bf16x8 vB3 = *(const bf16x8*)(vgb + 48);
    vgb += 64;

    // ---- softmax numerator + P write + partial l ----
    float rs = 0.f;
#pragma unroll
    for (int g = 0; g < 4; g++) {
      float p0 = exp2_raw(s0[4 * g]     + s1[4 * g]);
      float p1 = exp2_raw(s0[4 * g + 1] + s1[4 * g + 1]);
      float p2 = exp2_raw(s0[4 * g + 2] + s1[4 * g + 2]);
      float p3 = exp2_raw(s0[4 * g + 3] + s1[4 * g + 3]);
      rs += (p0 + p1) + (p2 + p3);
      uint2 d; d.x = cvt_pk_bf16(p0, p1); d.y = cvt_pk_bf16(p2, p3);
      *(uint2*)pwr[g] = d;
    }
    l_i += rs;

    // b1 (counted): P ds_writes visible + K ds_reads retired; no vmcnt drain
    asm volatile("s_waitcnt lgkmcnt(0)" ::: "memory");
    __builtin_amdgcn_s_barrier();

    // K[kt+1] DMA; drains at b2 behind PV
    if (kt < 31) {
#pragma unroll
      for (int rep = 0; rep < 8; rep++) {
        async16(kp[rep], klds + (w * 8 + rep) * 512);
        kp[rep] += 16384;
      }
    }

    // ---- O^T += V^T P^T ----
    bf16x8 pa[4], pb[4];
#pragma unroll
    for (int i = 0; i < 4; i++) {
      pa[i] = *(const bf16x8*)prdA[i];
      pb[i] = *(const bf16x8*)prdB[i];
    }
    __builtin_amdgcn_s_setprio(1);
    oacc[0] = __builtin_amdgcn_mfma_f32_32x32x16_bf16(va0, pa[0], oacc[0], 0, 0, 0);
    oacc[1] = __builtin_amdgcn_mfma_f32_32x32x16_bf16(va0, pb[0], oacc[1], 0, 0, 0);
    oacc[0] = __builtin_amdgcn_mfma_f32_32x32x16_bf16(va1, pa[1], oacc[0], 0, 0, 0);
    oacc[1] = __builtin_amdgcn_mfma_f32_32x32x16_bf16(va1, pb[1], oacc[1], 0, 0, 0);
    oacc[0] = __builtin_amdgcn_mfma_f32_32x32x16_bf16(va2, pa[2], oacc[0], 0, 0, 0);
    oacc[1] = __builtin_amdgcn_mfma_f32_32x32x16_bf16(va2, pb[2], oacc[1], 0, 0, 0);
    oacc[0] = __builtin_amdgcn_mfma_f32_32x32x16_bf16(va3, pa[3], oacc[0], 0, 0, 0);
    oacc[1] = __builtin_amdgcn_mfma_f32_32x32x16_bf16(va3, pb[3], oacc[1], 0, 0, 0);
    oacc[2] = __builtin_amdgcn_mfma_f32_32x32x16_bf16(vB0, pa[0], oacc[2], 0, 0, 0);
    oacc[3] = __builtin_amdgcn_mfma_f32_32x32x16_bf16(vB0, pb[0], oacc[3], 0, 0, 0);
    oacc[2] = __builtin_amdgcn_mfma_f32_32x32x16_bf16(vB1, pa[1], oacc[2], 0, 0, 0);
    oacc[3] = __builtin_amdgcn_mfma_f32_32x32x16_bf16(vB1, pb[1], oacc[3], 0, 0, 0);
    oacc[2] = __builtin_amdgcn_mfma_f32_32x32x16_bf16(vB2, pa[2], oacc[2], 0, 0, 0);
    oacc[3] = __builtin_amdgcn_mfma_f32_32x32x16_bf16(vB2, pb[2], oacc[3], 0, 0, 0);
    oacc[2] = __builtin_amdgcn_mfma_f32_32x32x16_bf16(vB3, pa[3], oacc[2], 0, 0, 0);
    oacc[3] = __builtin_amdgcn_mfma_f32_32x32x16_bf16(vB3, pb[3], oacc[3], 0, 0, 0);
    __builtin_amdgcn_s_setprio(0);
    __syncthreads();   // b2: P reads retired; K[kt+1] DMA drained
  }

  // ---- epilogue: merge l, normalize, transpose via LDS, store ----
  float lt = l_i + __shfl_xor(l_i, 32, 64);
  float* lbuf = (float*)(lds + 20224);   // disjoint from transpose region [0,16896)
  if (hi == 0) lbuf[(ct * 2 + qt) * 32 + lq] = lt;
  __syncthreads();
  float inv0 = 1.f / (lbuf[lq] + lbuf[64 + lq]);
  float inv1 = 1.f / (lbuf[32 + lq] + lbuf[96 + lq]);

#pragma unroll
  for (int ot = 0; ot < 4; ot++) {
    int qt2 = ot & 1, dt = ot >> 1;
    float inv = qt2 ? inv1 : inv0;
    int qg = qt2 * 32 + lq;
#pragma unroll
    for (int g = 0; g < 4; g++) {
      uint2 d;
      d.x = cvt_pk_bf16(oacc[ot][4 * g] * inv, oacc[ot][4 * g + 1] * inv);
      d.y = cvt_pk_bf16(oacc[ot][4 * g + 2] * inv, oacc[ot][4 * g + 3] * inv);
      *(uint2*)(lds + qg * 264 + w * 64 + dt * 32 + 8 * g + 4 * hi) = d;
    }
  }
  __syncthreads();
  short* obase = os + (((size_t)bb * 2048) + qb * 64) * 256;
#pragma unroll
  for (int rep = 0; rep < 8; rep++) {
    int cid = rep * 256 + tid;
    int row = cid >> 5, c = cid & 31;
    *(bf16x8*)(obase + row * 256 + c * 8) = *(const bf16x8*)(lds + row * 264 + c * 8);
  }
}

// ---- out = [O_L|O_H] @ w2^T + b_o : 128x128 tiles, BK=64, async-DMA double-buffered ----
__launch_bounds__(256, 2)
__global__ void out_gemm(const short* __restrict__ os, const short* __restrict__ w2,
                         const float* __restrict__ bo, float* __restrict__ out) {
  __shared__ short alds[2][8192];   // 128 rows x 64 k (xor-chunk swizzled)
  __shared__ short blds[2][8192];
  int tid = threadIdx.x;
  int w = tid >> 6, L = tid & 63, lo = L & 15, hi = L >> 4;
  int wr = w >> 1, wc = w & 1;
  int br = blockIdx.x, bc = blockIdx.y;

  // DMA lane geometry: op o = w*4+rep covers rows o*8..o*8+7, lane chunk L&7
  int rrow[4], rchk[4];
#pragma unroll
  for (int rep = 0; rep < 4; rep++) {
    int o = w * 4 + rep;
    int r = o * 8 + (L >> 3);
    rrow[rep] = r;
    rchk[rep] = ((L & 7) ^ (r & 7)) * 8;
  }
  int b = br >> 4;
  int s0 = (br & 15) * 128;
  const short* abase = os + ((size_t)(b * 2) * 2048 + s0) * 256;   // + half*2048*256 + row*256 + i0 + chk
  const short* bbase = w2 + (size_t)(bc * 128) * 512;              // + row*512 + kt*64 + chk

  f32x4 acc[4][4];
#pragma unroll
  for (int mt = 0; mt < 4; mt++)
#pragma unroll
    for (int nt = 0; nt < 4; nt++)
      acc[mt][nt] = (f32x4){0.f, 0.f, 0.f, 0.f};

  // frag read offsets (swizzle reduces to lo&7; rows multiple-of-16 apart)
  int fch[2];
#pragma unroll
  for (int kc = 0; kc < 2; kc++)
    fch[kc] = ((kc * 4 + hi) ^ (lo & 7)) * 8;

  // prologue: stage kt=0 into buf 0
#pragma unroll
  for (int rep = 0; rep < 4; rep++) {
    async16(abase + rrow[rep] * 256 + rchk[rep], &alds[0][(w * 4 + rep) * 512] + L * 8);
    async16(bbase + rrow[rep] * 512 + rchk[rep], &blds[0][(w * 4 + rep) * 512] + L * 8);
  }
  __syncthreads();

  int p = 0;
  for (int kt = 0; kt < 8; kt++) {
    if (kt < 7) {
      int k1 = kt + 1;
      int half = k1 >> 2, i0 = (k1 & 3) * 64;
      const short* ab = abase + (size_t)half * 2048 * 256 + i0;
#pragma unroll
      for (int rep = 0; rep < 4; rep++) {
        async16(ab + rrow[rep] * 256 + rchk[rep], &alds[p ^ 1][(w * 4 + rep) * 512] + L * 8);
        async16(bbase + rrow[rep] * 512 + k1 * 64 + rchk[rep], &blds[p ^ 1][(w * 4 + rep) * 512] + L * 8);
      }
    }
    bf16x8 af[4], bfr[4];
#pragma unroll
    for (int kc = 0; kc < 2; kc++) {
#pragma unroll
      for (int mt = 0; mt < 4; mt++)
        af[mt] = *(const bf16x8*)(&alds[p][(wr * 64 + mt * 16 + lo) * 64 + fch[kc]]);
#pragma unroll
      for (int nt = 0; nt < 4; nt++)
        bfr[nt] = *(const bf16x8*)(&blds[p][(wc * 64 + nt * 16 + lo) * 64 + fch[kc]]);
#pragma unroll
      for (int mt = 0; mt < 4; mt++)
#pragma unroll
        for (int nt = 0; nt < 4; nt++)
          acc[mt][nt] = __builtin_amdgcn_mfma_f32_16x16x32_bf16(af[mt], bfr[nt], acc[mt][nt], 0, 0, 0);
    }
    __syncthreads();   // reads of buf p done; DMA into p^1 drained
    p ^= 1;
  }

#pragma unroll
  for (int nt = 0; nt < 4; nt++) {
    int cc = bc * 128 + wc * 64 + nt * 16 + lo;
    float bias = bo[cc];
#pragma unroll
    for (int mt = 0; mt < 4; mt++) {
      int rrbase = br * 128 + wr * 64 + mt * 16 + hi * 4;
#pragma unroll
      for (int r = 0; r < 4; r++)
        out[(size_t)(rrbase + r) * 512 + cc] = acc[mt][nt][r] + bias;
    }
  }
}

extern "C" void kernel_launch(void* const* d_in, const int* in_sizes, int n_in,
                              void* d_out, int out_size, void* d_ws, size_t ws_size,
                              hipStream_t stream) {
  const float* q  = (const float*)d_in[0];
  const float* k  = (const float*)d_in[1];
  const float* v  = (const float*)d_in[2];
  const float* W  = (const float*)d_in[3];
  const float* bo = (const float*)d_in[4];
  short* ws  = (short*)d_ws;
  short* qs  = ws;
  short* ksb = ws + (size_t)8  * 1024 * 1024;
  short* vtp = ws + (size_t)16 * 1024 * 1024;
  short* osb = ws + (size_t)24 * 1024 * 1024;
  short* w2  = ws + (size_t)32 * 1024 * 1024;   // 512x512 bf16

  dwt_all<<<4224, 256, 0, stream>>>(q, k, v, W, qs, ksb, vtp, w2);
  flash_attn<<<dim3(16, 32), 256, 0, stream>>>(qs, ksb, vtp, osb);
  out_gemm<<<dim3(128, 4), 256, 0, stream>>>(osb, w2, bo, (float*)d_out);
}

// Round 4
// 245.181 us; speedup vs baseline: 1.0859x; 1.0299x over previous
//
#include <hip/hip_runtime.h>

#define INV_SQRT2 0.70710678118654752f
#define QSCALE    0.17677669529663689f   // 1/sqrt(HEAD_DIM=32)
#define LOG2E     1.44269504088896340f
#define SM_HALF   16.0f                  // softmax shift folded into acc init: s0,s1 each start at -16

typedef __attribute__((ext_vector_type(8))) short bf16x8;
typedef __attribute__((ext_vector_type(4))) float f32x4;
typedef __attribute__((ext_vector_type(16))) float f32x16;

// single-instruction packed f32->bf16 (RNE), dst.lo = bf16(a), dst.hi = bf16(b)
__device__ __forceinline__ unsigned cvt_pk_bf16(float a, float b) {
  unsigned r;
  asm("v_cvt_pk_bf16_f32 %0, %1, %2" : "=v"(r) : "v"(a), "v"(b));
  return r;
}

__device__ __forceinline__ float exp2_raw(float x) {
  float r;
  asm("v_exp_f32 %0, %1" : "=v"(r) : "v"(x));
  return r;
}

// async global->LDS, 16B per lane; LDS dest = wave-uniform base + lane*16
__device__ __forceinline__ void async16(const short* g, short* l) {
  typedef __attribute__((address_space(3))) unsigned lds_u32;
  typedef const __attribute__((address_space(1))) unsigned glb_u32;
  __builtin_amdgcn_global_load_lds((glb_u32*)g, (lds_u32*)l, 16, 0, 0);
}

// ---- fused pre-pass: DWT(q,k) + DWT(v)+transpose + iDWT-fused W_o, one launch ----
// branch 1 (V): 64s x 64d tiles, bf16 LDS staging, FULL 128B-line output writes
__launch_bounds__(256, 4)
__global__ void dwt_all(const float* __restrict__ q, const float* __restrict__ k,
                        const float* __restrict__ v, const float* __restrict__ W,
                        short* __restrict__ qs, short* __restrict__ ks,
                        short* __restrict__ vt, short* __restrict__ w2) {
  __shared__ short tLb[64][68];
  __shared__ short tHb[64][68];
  int bi = blockIdx.x;
  int t = threadIdx.x;
  if (bi < 2048) {
    int idx = bi * 256 + t;
    int j = idx & 31;
    int s = (idx >> 5) & 2047;
    int b = idx >> 16;
    const float4* qp = (const float4*)(q + ((size_t)(b * 2048 + s)) * 512 + j * 16);
    const float4* kp = (const float4*)(k + ((size_t)(b * 2048 + s)) * 512 + j * 16);
    float4 a0 = qp[0], a1 = qp[1], a2 = qp[2], a3 = qp[3];
    float4 c0 = kp[0], c1 = kp[1], c2 = kp[2], c3 = kp[3];
    union { bf16x8 v; unsigned u[4]; } qL, qH, kL, kH;
    const float cs = INV_SQRT2 * QSCALE * LOG2E;
    qL.u[0] = cvt_pk_bf16((a0.x + a0.y) * cs, (a0.z + a0.w) * cs);
    qL.u[1] = cvt_pk_bf16((a1.x + a1.y) * cs, (a1.z + a1.w) * cs);
    qL.u[2] = cvt_pk_bf16((a2.x + a2.y) * cs, (a2.z + a2.w) * cs);
    qL.u[3] = cvt_pk_bf16((a3.x + a3.y) * cs, (a3.z + a3.w) * cs);
    qH.u[0] = cvt_pk_bf16((a0.x - a0.y) * cs, (a0.z - a0.w) * cs);
    qH.u[1] = cvt_pk_bf16((a1.x - a1.y) * cs, (a1.z - a1.w) * cs);
    qH.u[2] = cvt_pk_bf16((a2.x - a2.y) * cs, (a2.z - a2.w) * cs);
    qH.u[3] = cvt_pk_bf16((a3.x - a3.y) * cs, (a3.z - a3.w) * cs);
    kL.u[0] = cvt_pk_bf16((c0.x + c0.y) * INV_SQRT2, (c0.z + c0.w) * INV_SQRT2);
    kL.u[1] = cvt_pk_bf16((c1.x + c1.y) * INV_SQRT2, (c1.z + c1.w) * INV_SQRT2);
    kL.u[2] = cvt_pk_bf16((c2.x + c2.y) * INV_SQRT2, (c2.z + c2.w) * INV_SQRT2);
    kL.u[3] = cvt_pk_bf16((c3.x + c3.y) * INV_SQRT2, (c3.z + c3.w) * INV_SQRT2);
    kH.u[0] = cvt_pk_bf16((c0.x - c0.y) * INV_SQRT2, (c0.z - c0.w) * INV_SQRT2);
    kH.u[1] = cvt_pk_bf16((c1.x - c1.y) * INV_SQRT2, (c1.z - c1.w) * INV_SQRT2);
    kH.u[2] = cvt_pk_bf16((c2.x - c2.y) * INV_SQRT2, (c2.z - c2.w) * INV_SQRT2);
    kH.u[3] = cvt_pk_bf16((c3.x - c3.y) * INV_SQRT2, (c3.z - c3.w) * INV_SQRT2);
    size_t oL = ((size_t)(b * 2) * 2048 + s) * 256 + j * 8;
    size_t oH = oL + (size_t)2048 * 256;
    *(bf16x8*)(qs + oL) = qL.v;  *(bf16x8*)(qs + oH) = qH.v;
    *(bf16x8*)(ks + oL) = kL.v;  *(bf16x8*)(ks + oH) = kH.v;
  } else if (bi < 3072) {
    int bi2 = bi - 2048;                 // 1024 blocks: 8 b x 32 st x 4 it
    int it = bi2 & 3, st = (bi2 >> 2) & 31, b = bi2 >> 7;
    const float* vsrc = v + ((size_t)(b * 2048 + st * 64)) * 512 + it * 128;
#pragma unroll
    for (int rep = 0; rep < 8; rep++) {
      int u = rep * 256 + t;
      int r = u >> 5, c4 = u & 31;
      float4 vv = *(const float4*)(vsrc + (size_t)r * 512 + c4 * 4);
      *(unsigned*)&tLb[r][c4 * 2] = cvt_pk_bf16((vv.x + vv.y) * INV_SQRT2, (vv.z + vv.w) * INV_SQRT2);
      *(unsigned*)&tHb[r][c4 * 2] = cvt_pk_bf16((vv.x - vv.y) * INV_SQRT2, (vv.z - vv.w) * INV_SQRT2);
    }
    __syncthreads();
    short* vtb = vt + ((size_t)(b * 2) * 256 + it * 64) * 2048 + st * 64;
#pragma unroll
    for (int rep = 0; rep < 2; rep++) {
      int u = rep * 256 + t;           // 512 units: 32 ipair x 8 g x 2 lh
      int ip = u & 31, g = (u >> 5) & 7, lh = u >> 8;
      const short (*tile)[68] = lh ? tHb : tLb;
      union { bf16x8 v; unsigned short e[8]; } o0, o1;
#pragma unroll
      for (int j = 0; j < 8; j++) {
        unsigned wv = *(const unsigned*)&tile[g * 8 + j][ip * 2];
        o0.e[j] = (unsigned short)wv;
        o1.e[j] = (unsigned short)(wv >> 16);
      }
      short* dst = vtb + (size_t)lh * 256 * 2048 + (size_t)(ip * 2) * 2048 + g * 8;
      *(bf16x8*)dst = o0.v;
      *(bf16x8*)(dst + 2048) = o1.v;
    }
  } else {
    int idx = (bi - 3072) * 256 + t;
    int j = idx >> 6, i4 = (idx & 63) * 4;
    const float4* src = (const float4*)(W + (size_t)j * 512 + 2 * i4);
    float4 f0 = src[0], f1 = src[1];
    uint2 dl, dh;
    dl.x = cvt_pk_bf16((f0.x + f0.y) * INV_SQRT2, (f0.z + f0.w) * INV_SQRT2);
    dl.y = cvt_pk_bf16((f1.x + f1.y) * INV_SQRT2, (f1.z + f1.w) * INV_SQRT2);
    dh.x = cvt_pk_bf16((f0.x - f0.y) * INV_SQRT2, (f0.z - f0.w) * INV_SQRT2);
    dh.y = cvt_pk_bf16((f1.x - f1.y) * INV_SQRT2, (f1.z - f1.w) * INV_SQRT2);
    *(uint2*)(w2 + (size_t)j * 512 + i4) = dl;
    *(uint2*)(w2 + (size_t)j * 512 + 256 + i4) = dh;
  }
}

// ---- flash attention (R1 structure, best measured): V in LDS via async DMA ----
// S: wave (ct,qt) computes kv32 x q32. PV: wave w computes d[w*64..+64) x q64.
// LDS (shorts): K [0,16384) | V^T [16384,32768) | P [32768,36864)
__launch_bounds__(256, 2)
__global__ void flash_attn(const short* __restrict__ qs, const short* __restrict__ ks,
                           const short* __restrict__ vt, short* __restrict__ os) {
  __shared__ short lds[36864];
  short* klds = lds;
  short* vlds = lds + 16384;
  short* plds = lds + 32768;

  int tid = threadIdx.x;
  int w = tid >> 6, L = tid & 63;
  int lq = L & 31, hi = L >> 5;
  int qt = w & 1, ct = w >> 1;
  int bb = blockIdx.x, qb = blockIdx.y;  // bb fastest -> XCD L2 locality on K/V

  // Q as B-operand fragments: B[k = hi*8+j][n = lq]
  bf16x8 qf[16];
  const short* qptr = qs + (((size_t)bb * 2048) + qb * 64 + qt * 32 + lq) * 256 + hi * 8;
#pragma unroll
  for (int ksI = 0; ksI < 16; ksI++)
    qf[ksI] = *(const bf16x8*)(qptr + ksI * 16);

  f32x16 oacc[4];   // [dt*2+qt2]: d = w*64+dt*32+rows, q = qt2*32+lq
#pragma unroll
  for (int mt = 0; mt < 4; mt++)
#pragma unroll
    for (int i = 0; i < 16; i++) oacc[mt][i] = 0.f;
  float l_i = 0.f;

  const short* kbase = ks + ((size_t)bb * 2048) * 256;
  const short* vbase = vt + ((size_t)bb * 256) * 2048;

  int krow = ct * 32 + lq, ksw = krow & 7;
  int qrow = qt * 32 + lq, qsw = qrow & 7;
  int sw8 = lq & 7;

  // ---- hoisted loop-invariant LDS addresses ----
  const short* kaddr[16];
#pragma unroll
  for (int i = 0; i < 16; i++)
    kaddr[i] = klds + krow * 256 + (((i << 1) | hi) ^ ksw) * 8;
  short* pwr[4];
#pragma unroll
  for (int g = 0; g < 4; g++)
    pwr[g] = plds + qrow * 64 + ((4 * ct + g) ^ qsw) * 8 + hi * 4;
  const short* prdA[4];   // P reads for q-half 0 (rows lq)
  const short* prdB[4];   // q-half 1 (rows 32+lq)
#pragma unroll
  for (int i = 0; i < 4; i++) {
    int ch = (((i << 1) | hi) ^ sw8) * 8;
    prdA[i] = plds + lq * 64 + ch;
    prdB[i] = plds + (32 + lq) * 64 + ch;
  }
  int vch[4];
#pragma unroll
  for (int i = 0; i < 4; i++)
    vch[i] = (((i << 1) | hi) ^ sw8) * 8;
  const short* vrowp[2];
#pragma unroll
  for (int dt = 0; dt < 2; dt++)
    vrowp[dt] = vlds + (w * 64 + dt * 32 + lq) * 64;

  // ---- hoisted DMA source pointers ----
  const short* kp[8];
  const short* vp[8];
#pragma unroll
  for (int rep = 0; rep < 8; rep++) {
    int o = w * 8 + rep;
    int r = 2 * o + (L >> 5);
    int c = (L & 31) ^ (r & 7);
    kp[rep] = kbase + r * 256 + c * 8;
    int n = 8 * o + (L >> 3);
    int cv = (L & 7) ^ (n & 7);
    vp[rep] = vbase + n * 2048 + cv * 8;
  }

  // prologue: stage K[0]
#pragma unroll
  for (int rep = 0; rep < 8; rep++) {
    async16(kp[rep], klds + (w * 8 + rep) * 512);
    kp[rep] += 16384;
  }
  __syncthreads();

  for (int kt = 0; kt < 32; kt++) {
    // V[kt] DMA (region retired at prev b2); drains at b1 behind S phase
#pragma unroll
    for (int rep = 0; rep < 8; rep++) {
      async16(vp[rep], vlds + (w * 8 + rep) * 512);
      vp[rep] += 64;
    }

    // ---- S^T tile: two interleaved accumulator chains; softmax shift pre-folded ----
    f32x16 s0, s1;
#pragma unroll
    for (int i = 0; i < 16; i++) { s0[i] = -SM_HALF; s1[i] = -SM_HALF; }
    __builtin_amdgcn_s_setprio(1);
#pragma unroll
    for (int ksI = 0; ksI < 16; ksI += 2) {
      bf16x8 kb0 = *(const bf16x8*)kaddr[ksI];
      bf16x8 kb1 = *(const bf16x8*)kaddr[ksI + 1];
      s0 = __builtin_amdgcn_mfma_f32_32x32x16_bf16(kb0, qf[ksI], s0, 0, 0, 0);
      s1 = __builtin_amdgcn_mfma_f32_32x32x16_bf16(kb1, qf[ksI + 1], s1, 0, 0, 0);
    }
    __builtin_amdgcn_s_setprio(0);

    // ---- softmax numerator + P write + partial l ----
    float rs = 0.f;
#pragma unroll
    for (int g = 0; g < 4; g++) {
      float p0 = exp2_raw(s0[4 * g]     + s1[4 * g]);
      float p1 = exp2_raw(s0[4 * g + 1] + s1[4 * g + 1]);
      float p2 = exp2_raw(s0[4 * g + 2] + s1[4 * g + 2]);
      float p3 = exp2_raw(s0[4 * g + 3] + s1[4 * g + 3]);
      rs += (p0 + p1) + (p2 + p3);
      uint2 d; d.x = cvt_pk_bf16(p0, p1); d.y = cvt_pk_bf16(p2, p3);
      *(uint2*)pwr[g] = d;
    }
    l_i += rs;
    __syncthreads();   // b1: P visible; V[kt] drained; K reads done

    // K[kt+1] DMA; drains at b2 behind PV
    if (kt < 31) {
#pragma unroll
      for (int rep = 0; rep < 8; rep++) {
        async16(kp[rep], klds + (w * 8 + rep) * 512);
        kp[rep] += 16384;
      }
    }

    // ---- O^T += V^T P^T, 2x2: each vb/pb frag used twice ----
    bf16x8 pa[4], pb[4];
#pragma unroll
    for (int i = 0; i < 4; i++) {
      pa[i] = *(const bf16x8*)prdA[i];
      pb[i] = *(const bf16x8*)prdB[i];
    }
    __builtin_amdgcn_s_setprio(1);
#pragma unroll
    for (int dt = 0; dt < 2; dt++) {
#pragma unroll
      for (int i = 0; i < 4; i++) {
        bf16x8 vb = *(const bf16x8*)(vrowp[dt] + vch[i]);
        oacc[dt * 2]     = __builtin_amdgcn_mfma_f32_32x32x16_bf16(vb, pa[i], oacc[dt * 2], 0, 0, 0);
        oacc[dt * 2 + 1] = __builtin_amdgcn_mfma_f32_32x32x16_bf16(vb, pb[i], oacc[dt * 2 + 1], 0, 0, 0);
      }
    }
    __builtin_amdgcn_s_setprio(0);
    __syncthreads();   // b2: V/P reads retired; K[kt+1] drained
  }

  // ---- epilogue: merge l, normalize, transpose via LDS, store ----
  float lt = l_i + __shfl_xor(l_i, 32, 64);
  float* lbuf = (float*)plds;
  if (hi == 0) lbuf[(ct * 2 + qt) * 32 + lq] = lt;
  __syncthreads();
  float inv0 = 1.f / (lbuf[lq] + lbuf[64 + lq]);
  float inv1 = 1.f / (lbuf[32 + lq] + lbuf[96 + lq]);

#pragma unroll
  for (int ot = 0; ot < 4; ot++) {
    int qt2 = ot & 1, dt = ot >> 1;
    float inv = qt2 ? inv1 : inv0;
    int qg = qt2 * 32 + lq;
#pragma unroll
    for (int g = 0; g < 4; g++) {
      uint2 d;
      d.x = cvt_pk_bf16(oacc[ot][4 * g] * inv, oacc[ot][4 * g + 1] * inv);
      d.y = cvt_pk_bf16(oacc[ot][4 * g + 2] * inv, oacc[ot][4 * g + 3] * inv);
      *(uint2*)(lds + qg * 264 + w * 64 + dt * 32 + 8 * g + 4 * hi) = d;
    }
  }
  __syncthreads();
  short* obase = os + (((size_t)bb * 2048) + qb * 64) * 256;
#pragma unroll
  for (int rep = 0; rep < 8; rep++) {
    int cid = rep * 256 + tid;
    int row = cid >> 5, c = cid & 31;
    *(bf16x8*)(obase + row * 256 + c * 8) = *(const bf16x8*)(lds + row * 264 + c * 8);
  }
}

// ---- out = [O_L|O_H] @ w2^T + b_o : 128x128 tiles, BK=64, async-DMA double-buffered ----
__launch_bounds__(256, 2)
__global__ void out_gemm(const short* __restrict__ os, const short* __restrict__ w2,
                         const float* __restrict__ bo, float* __restrict__ out) {
  __shared__ short alds[2][8192];   // 128 rows x 64 k (xor-chunk swizzled)
  __shared__ short blds[2][8192];
  int tid = threadIdx.x;
  int w = tid >> 6, L = tid & 63, lo = L & 15, hi = L >> 4;
  int wr = w >> 1, wc = w & 1;
  int br = blockIdx.x, bc = blockIdx.y;

  // DMA lane geometry: op o = w*4+rep covers rows o*8..o*8+7, lane chunk L&7
  int rrow[4], rchk[4];
#pragma unroll
  for (int rep = 0; rep < 4; rep++) {
    int o = w * 4 + rep;
    int r = o * 8 + (L >> 3);
    rrow[rep] = r;
    rchk[rep] = ((L & 7) ^ (r & 7)) * 8;
  }
  int b = br >> 4;
  int s0 = (br & 15) * 128;
  const short* abase = os + ((size_t)(b * 2) * 2048 + s0) * 256;   // + half*2048*256 + row*256 + i0 + chk
  const short* bbase = w2 + (size_t)(bc * 128) * 512;              // + row*512 + kt*64 + chk

  f32x4 acc[4][4];
#pragma unroll
  for (int mt = 0; mt < 4; mt++)
#pragma unroll
    for (int nt = 0; nt < 4; nt++)
      acc[mt][nt] = (f32x4){0.f, 0.f, 0.f, 0.f};

  // frag read offsets (swizzle reduces to lo&7; rows multiple-of-16 apart)
  int fch[2];
#pragma unroll
  for (int kc = 0; kc < 2; kc++)
    fch[kc] = ((kc * 4 + hi) ^ (lo & 7)) * 8;

  // prologue: stage kt=0 into buf 0
#pragma unroll
  for (int rep = 0; rep < 4; rep++) {
    async16(abase + rrow[rep] * 256 + rchk[rep], &alds[0][(w * 4 + rep) * 512] + L * 8);
    async16(bbase + rrow[rep] * 512 + rchk[rep], &blds[0][(w * 4 + rep) * 512] + L * 8);
  }
  __syncthreads();

  int p = 0;
  for (int kt = 0; kt < 8; kt++) {
    if (kt < 7) {
      int k1 = kt + 1;
      int half = k1 >> 2, i0 = (k1 & 3) * 64;
      const short* ab = abase + (size_t)half * 2048 * 256 + i0;
#pragma unroll
      for (int rep = 0; rep < 4; rep++) {
        async16(ab + rrow[rep] * 256 + rchk[rep], &alds[p ^ 1][(w * 4 + rep) * 512] + L * 8);
        async16(bbase + rrow[rep] * 512 + k1 * 64 + rchk[rep], &blds[p ^ 1][(w * 4 + rep) * 512] + L * 8);
      }
    }
    bf16x8 af[4], bfr[4];
#pragma unroll
    for (int kc = 0; kc < 2; kc++) {
#pragma unroll
      for (int mt = 0; mt < 4; mt++)
        af[mt] = *(const bf16x8*)(&alds[p][(wr * 64 + mt * 16 + lo) * 64 + fch[kc]]);
#pragma unroll
      for (int nt = 0; nt < 4; nt++)
        bfr[nt] = *(const bf16x8*)(&blds[p][(wc * 64 + nt * 16 + lo) * 64 + fch[kc]]);
#pragma unroll
      for (int mt = 0; mt < 4; mt++)
#pragma unroll
        for (int nt = 0; nt < 4; nt++)
          acc[mt][nt] = __builtin_amdgcn_mfma_f32_16x16x32_bf16(af[mt], bfr[nt], acc[mt][nt], 0, 0, 0);
    }
    __syncthreads();   // reads of buf p done; DMA into p^1 drained
    p ^= 1;
  }

#pragma unroll
  for (int nt = 0; nt < 4; nt++) {
    int cc = bc * 128 + wc * 64 + nt * 16 + lo;
    float bias = bo[cc];
#pragma unroll
    for (int mt = 0; mt < 4; mt++) {
      int rrbase = br * 128 + wr * 64 + mt * 16 + hi * 4;
#pragma unroll
      for (int r = 0; r < 4; r++)
        out[(size_t)(rrbase + r) * 512 + cc] = acc[mt][nt][r] + bias;
    }
  }
}

extern "C" void kernel_launch(void* const* d_in, const int* in_sizes, int n_in,
                              void* d_out, int out_size, void* d_ws, size_t ws_size,
                              hipStream_t stream) {
  const float* q  = (const float*)d_in[0];
  const float* k  = (const float*)d_in[1];
  const float* v  = (const float*)d_in[2];
  const float* W  = (const float*)d_in[3];
  const float* bo = (const float*)d_in[4];
  short* ws  = (short*)d_ws;
  short* qs  = ws;
  short* ksb = ws + (size_t)8  * 1024 * 1024;
  short* vtp = ws + (size_t)16 * 1024 * 1024;
  short* osb = ws + (size_t)24 * 1024 * 1024;
  short* w2  = ws + (size_t)32 * 1024 * 1024;   // 512x512 bf16

  dwt_all<<<3200, 256, 0, stream>>>(q, k, v, W, qs, ksb, vtp, w2);
  flash_attn<<<dim3(16, 32), 256, 0, stream>>>(qs, ksb, vtp, osb);
  out_gemm<<<dim3(128, 4), 256, 0, stream>>>(osb, w2, bo, (float*)d_out);
}

// Round 5
// 241.809 us; speedup vs baseline: 1.1011x; 1.0139x over previous
//
#include <hip/hip_runtime.h>

#define INV_SQRT2 0.70710678118654752f
#define QSCALE    0.17677669529663689f   // 1/sqrt(HEAD_DIM=32)
#define LOG2E     1.44269504088896340f
#define SM_HALF   16.0f                  // softmax shift folded into acc init: s0,s1 each start at -16

typedef __attribute__((ext_vector_type(8))) short bf16x8;
typedef __attribute__((ext_vector_type(4))) float f32x4;
typedef __attribute__((ext_vector_type(16))) float f32x16;

// single-instruction packed f32->bf16 (RNE), dst.lo = bf16(a), dst.hi = bf16(b)
__device__ __forceinline__ unsigned cvt_pk_bf16(float a, float b) {
  unsigned r;
  asm("v_cvt_pk_bf16_f32 %0, %1, %2" : "=v"(r) : "v"(a), "v"(b));
  return r;
}

__device__ __forceinline__ float exp2_raw(float x) {
  float r;
  asm("v_exp_f32 %0, %1" : "=v"(r) : "v"(x));
  return r;
}

// async global->LDS, 16B per lane; LDS dest = wave-uniform base + lane*16
__device__ __forceinline__ void async16(const short* g, short* l) {
  typedef __attribute__((address_space(3))) unsigned lds_u32;
  typedef const __attribute__((address_space(1))) unsigned glb_u32;
  __builtin_amdgcn_global_load_lds((glb_u32*)g, (lds_u32*)l, 16, 0, 0);
}

// ---- fused pre-pass: DWT(q,k) + DWT(v)+transpose + iDWT-fused W_o, one launch ----
// no launch_bounds: branch 0 needs ~50 live VGPRs; a (256,4) cap risks scratch spill
__global__ void dwt_all(const float* __restrict__ q, const float* __restrict__ k,
                        const float* __restrict__ v, const float* __restrict__ W,
                        short* __restrict__ qs, short* __restrict__ ks,
                        short* __restrict__ vt, short* __restrict__ w2) {
  __shared__ short tLb[64][68];
  __shared__ short tHb[64][68];
  int bi = blockIdx.x;
  int t = threadIdx.x;
  if (bi < 2048) {
    int idx = bi * 256 + t;
    int j = idx & 31;
    int s = (idx >> 5) & 2047;
    int b = idx >> 16;
    const float4* qp = (const float4*)(q + ((size_t)(b * 2048 + s)) * 512 + j * 16);
    const float4* kp = (const float4*)(k + ((size_t)(b * 2048 + s)) * 512 + j * 16);
    float4 a0 = qp[0], a1 = qp[1], a2 = qp[2], a3 = qp[3];
    float4 c0 = kp[0], c1 = kp[1], c2 = kp[2], c3 = kp[3];
    union { bf16x8 v; unsigned u[4]; } qL, qH, kL, kH;
    const float cs = INV_SQRT2 * QSCALE * LOG2E;
    qL.u[0] = cvt_pk_bf16((a0.x + a0.y) * cs, (a0.z + a0.w) * cs);
    qL.u[1] = cvt_pk_bf16((a1.x + a1.y) * cs, (a1.z + a1.w) * cs);
    qL.u[2] = cvt_pk_bf16((a2.x + a2.y) * cs, (a2.z + a2.w) * cs);
    qL.u[3] = cvt_pk_bf16((a3.x + a3.y) * cs, (a3.z + a3.w) * cs);
    qH.u[0] = cvt_pk_bf16((a0.x - a0.y) * cs, (a0.z - a0.w) * cs);
    qH.u[1] = cvt_pk_bf16((a1.x - a1.y) * cs, (a1.z - a1.w) * cs);
    qH.u[2] = cvt_pk_bf16((a2.x - a2.y) * cs, (a2.z - a2.w) * cs);
    qH.u[3] = cvt_pk_bf16((a3.x - a3.y) * cs, (a3.z - a3.w) * cs);
    kL.u[0] = cvt_pk_bf16((c0.x + c0.y) * INV_SQRT2, (c0.z + c0.w) * INV_SQRT2);
    kL.u[1] = cvt_pk_bf16((c1.x + c1.y) * INV_SQRT2, (c1.z + c1.w) * INV_SQRT2);
    kL.u[2] = cvt_pk_bf16((c2.x + c2.y) * INV_SQRT2, (c2.z + c2.w) * INV_SQRT2);
    kL.u[3] = cvt_pk_bf16((c3.x + c3.y) * INV_SQRT2, (c3.z + c3.w) * INV_SQRT2);
    kH.u[0] = cvt_pk_bf16((c0.x - c0.y) * INV_SQRT2, (c0.z - c0.w) * INV_SQRT2);
    kH.u[1] = cvt_pk_bf16((c1.x - c1.y) * INV_SQRT2, (c1.z - c1.w) * INV_SQRT2);
    kH.u[2] = cvt_pk_bf16((c2.x - c2.y) * INV_SQRT2, (c2.z - c2.w) * INV_SQRT2);
    kH.u[3] = cvt_pk_bf16((c3.x - c3.y) * INV_SQRT2, (c3.z - c3.w) * INV_SQRT2);
    size_t oL = ((size_t)(b * 2) * 2048 + s) * 256 + j * 8;
    size_t oH = oL + (size_t)2048 * 256;
    *(bf16x8*)(qs + oL) = qL.v;  *(bf16x8*)(qs + oH) = qH.v;
    *(bf16x8*)(ks + oL) = kL.v;  *(bf16x8*)(ks + oH) = kH.v;
  } else if (bi < 3072) {
    int bi2 = bi - 2048;                 // 1024 blocks: 8 b x 32 st x 4 it
    int it = bi2 & 3, st = (bi2 >> 2) & 31, b = bi2 >> 7;
    const float* vsrc = v + ((size_t)(b * 2048 + st * 64)) * 512 + it * 128;
#pragma unroll
    for (int rep = 0; rep < 8; rep++) {
      int u = rep * 256 + t;
      int r = u >> 5, c4 = u & 31;
      float4 vv = *(const float4*)(vsrc + (size_t)r * 512 + c4 * 4);
      *(unsigned*)&tLb[r][c4 * 2] = cvt_pk_bf16((vv.x + vv.y) * INV_SQRT2, (vv.z + vv.w) * INV_SQRT2);
      *(unsigned*)&tHb[r][c4 * 2] = cvt_pk_bf16((vv.x - vv.y) * INV_SQRT2, (vv.z - vv.w) * INV_SQRT2);
    }
    __syncthreads();
    short* vtb = vt + ((size_t)(b * 2) * 256 + it * 64) * 2048 + st * 64;
#pragma unroll
    for (int rep = 0; rep < 2; rep++) {
      int u = rep * 256 + t;           // 512 units: 32 ipair x 8 g x 2 lh
      int ip = u & 31, g = (u >> 5) & 7, lh = u >> 8;
      const short (*tile)[68] = lh ? tHb : tLb;
      union { bf16x8 v; unsigned short e[8]; } o0, o1;
#pragma unroll
      for (int j = 0; j < 8; j++) {
        unsigned wv = *(const unsigned*)&tile[g * 8 + j][ip * 2];
        o0.e[j] = (unsigned short)wv;
        o1.e[j] = (unsigned short)(wv >> 16);
      }
      short* dst = vtb + (size_t)lh * 256 * 2048 + (size_t)(ip * 2) * 2048 + g * 8;
      *(bf16x8*)dst = o0.v;
      *(bf16x8*)(dst + 2048) = o1.v;
    }
  } else {
    int idx = (bi - 3072) * 256 + t;
    int j = idx >> 6, i4 = (idx & 63) * 4;
    const float4* src = (const float4*)(W + (size_t)j * 512 + 2 * i4);
    float4 f0 = src[0], f1 = src[1];
    uint2 dl, dh;
    dl.x = cvt_pk_bf16((f0.x + f0.y) * INV_SQRT2, (f0.z + f0.w) * INV_SQRT2);
    dl.y = cvt_pk_bf16((f1.x + f1.y) * INV_SQRT2, (f1.z + f1.w) * INV_SQRT2);
    dh.x = cvt_pk_bf16((f0.x - f0.y) * INV_SQRT2, (f0.z - f0.w) * INV_SQRT2);
    dh.y = cvt_pk_bf16((f1.x - f1.y) * INV_SQRT2, (f1.z - f1.w) * INV_SQRT2);
    *(uint2*)(w2 + (size_t)j * 512 + i4) = dl;
    *(uint2*)(w2 + (size_t)j * 512 + 256 + i4) = dh;
  }
}

// ---- flash attention (R4 structure, UNCHANGED — control for this round) ----
// S: wave (ct,qt) computes kv32 x q32. PV: wave w computes d[w*64..+64) x q64.
// LDS (shorts): K [0,16384) | V^T [16384,32768) | P [32768,36864)
__launch_bounds__(256, 2)
__global__ void flash_attn(const short* __restrict__ qs, const short* __restrict__ ks,
                           const short* __restrict__ vt, short* __restrict__ os) {
  __shared__ short lds[36864];
  short* klds = lds;
  short* vlds = lds + 16384;
  short* plds = lds + 32768;

  int tid = threadIdx.x;
  int w = tid >> 6, L = tid & 63;
  int lq = L & 31, hi = L >> 5;
  int qt = w & 1, ct = w >> 1;
  int bb = blockIdx.x, qb = blockIdx.y;  // bb fastest -> XCD L2 locality on K/V

  // Q as B-operand fragments: B[k = hi*8+j][n = lq]
  bf16x8 qf[16];
  const short* qptr = qs + (((size_t)bb * 2048) + qb * 64 + qt * 32 + lq) * 256 + hi * 8;
#pragma unroll
  for (int ksI = 0; ksI < 16; ksI++)
    qf[ksI] = *(const bf16x8*)(qptr + ksI * 16);

  f32x16 oacc[4];   // [dt*2+qt2]: d = w*64+dt*32+rows, q = qt2*32+lq
#pragma unroll
  for (int mt = 0; mt < 4; mt++)
#pragma unroll
    for (int i = 0; i < 16; i++) oacc[mt][i] = 0.f;
  float l_i = 0.f;

  const short* kbase = ks + ((size_t)bb * 2048) * 256;
  const short* vbase = vt + ((size_t)bb * 256) * 2048;

  int krow = ct * 32 + lq, ksw = krow & 7;
  int qrow = qt * 32 + lq, qsw = qrow & 7;
  int sw8 = lq & 7;

  // ---- hoisted loop-invariant LDS addresses ----
  const short* kaddr[16];
#pragma unroll
  for (int i = 0; i < 16; i++)
    kaddr[i] = klds + krow * 256 + (((i << 1) | hi) ^ ksw) * 8;
  short* pwr[4];
#pragma unroll
  for (int g = 0; g < 4; g++)
    pwr[g] = plds + qrow * 64 + ((4 * ct + g) ^ qsw) * 8 + hi * 4;
  const short* prdA[4];   // P reads for q-half 0 (rows lq)
  const short* prdB[4];   // q-half 1 (rows 32+lq)
#pragma unroll
  for (int i = 0; i < 4; i++) {
    int ch = (((i << 1) | hi) ^ sw8) * 8;
    prdA[i] = plds + lq * 64 + ch;
    prdB[i] = plds + (32 + lq) * 64 + ch;
  }
  int vch[4];
#pragma unroll
  for (int i = 0; i < 4; i++)
    vch[i] = (((i << 1) | hi) ^ sw8) * 8;
  const short* vrowp[2];
#pragma unroll
  for (int dt = 0; dt < 2; dt++)
    vrowp[dt] = vlds + (w * 64 + dt * 32 + lq) * 64;

  // ---- hoisted DMA source pointers ----
  const short* kp[8];
  const short* vp[8];
#pragma unroll
  for (int rep = 0; rep < 8; rep++) {
    int o = w * 8 + rep;
    int r = 2 * o + (L >> 5);
    int c = (L & 31) ^ (r & 7);
    kp[rep] = kbase + r * 256 + c * 8;
    int n = 8 * o + (L >> 3);
    int cv = (L & 7) ^ (n & 7);
    vp[rep] = vbase + n * 2048 + cv * 8;
  }

  // prologue: stage K[0]
#pragma unroll
  for (int rep = 0; rep < 8; rep++) {
    async16(kp[rep], klds + (w * 8 + rep) * 512);
    kp[rep] += 16384;
  }
  __syncthreads();

  for (int kt = 0; kt < 32; kt++) {
    // V[kt] DMA (region retired at prev b2); drains at b1 behind S phase
#pragma unroll
    for (int rep = 0; rep < 8; rep++) {
      async16(vp[rep], vlds + (w * 8 + rep) * 512);
      vp[rep] += 64;
    }

    // ---- S^T tile: two interleaved accumulator chains; softmax shift pre-folded ----
    f32x16 s0, s1;
#pragma unroll
    for (int i = 0; i < 16; i++) { s0[i] = -SM_HALF; s1[i] = -SM_HALF; }
    __builtin_amdgcn_s_setprio(1);
#pragma unroll
    for (int ksI = 0; ksI < 16; ksI += 2) {
      bf16x8 kb0 = *(const bf16x8*)kaddr[ksI];
      bf16x8 kb1 = *(const bf16x8*)kaddr[ksI + 1];
      s0 = __builtin_amdgcn_mfma_f32_32x32x16_bf16(kb0, qf[ksI], s0, 0, 0, 0);
      s1 = __builtin_amdgcn_mfma_f32_32x32x16_bf16(kb1, qf[ksI + 1], s1, 0, 0, 0);
    }
    __builtin_amdgcn_s_setprio(0);

    // ---- softmax numerator + P write + partial l ----
    float rs = 0.f;
#pragma unroll
    for (int g = 0; g < 4; g++) {
      float p0 = exp2_raw(s0[4 * g]     + s1[4 * g]);
      float p1 = exp2_raw(s0[4 * g + 1] + s1[4 * g + 1]);
      float p2 = exp2_raw(s0[4 * g + 2] + s1[4 * g + 2]);
      float p3 = exp2_raw(s0[4 * g + 3] + s1[4 * g + 3]);
      rs += (p0 + p1) + (p2 + p3);
      uint2 d; d.x = cvt_pk_bf16(p0, p1); d.y = cvt_pk_bf16(p2, p3);
      *(uint2*)pwr[g] = d;
    }
    l_i += rs;
    __syncthreads();   // b1: P visible; V[kt] drained; K reads done

    // K[kt+1] DMA; drains at b2 behind PV
    if (kt < 31) {
#pragma unroll
      for (int rep = 0; rep < 8; rep++) {
        async16(kp[rep], klds + (w * 8 + rep) * 512);
        kp[rep] += 16384;
      }
    }

    // ---- O^T += V^T P^T, 2x2: each vb/pb frag used twice ----
    bf16x8 pa[4], pb[4];
#pragma unroll
    for (int i = 0; i < 4; i++) {
      pa[i] = *(const bf16x8*)prdA[i];
      pb[i] = *(const bf16x8*)prdB[i];
    }
    __builtin_amdgcn_s_setprio(1);
#pragma unroll
    for (int dt = 0; dt < 2; dt++) {
#pragma unroll
      for (int i = 0; i < 4; i++) {
        bf16x8 vb = *(const bf16x8*)(vrowp[dt] + vch[i]);
        oacc[dt * 2]     = __builtin_amdgcn_mfma_f32_32x32x16_bf16(vb, pa[i], oacc[dt * 2], 0, 0, 0);
        oacc[dt * 2 + 1] = __builtin_amdgcn_mfma_f32_32x32x16_bf16(vb, pb[i], oacc[dt * 2 + 1], 0, 0, 0);
      }
    }
    __builtin_amdgcn_s_setprio(0);
    __syncthreads();   // b2: V/P reads retired; K[kt+1] drained
  }

  // ---- epilogue: merge l, normalize, transpose via LDS, store ----
  float lt = l_i + __shfl_xor(l_i, 32, 64);
  float* lbuf = (float*)plds;
  if (hi == 0) lbuf[(ct * 2 + qt) * 32 + lq] = lt;
  __syncthreads();
  float inv0 = 1.f / (lbuf[lq] + lbuf[64 + lq]);
  float inv1 = 1.f / (lbuf[32 + lq] + lbuf[96 + lq]);

#pragma unroll
  for (int ot = 0; ot < 4; ot++) {
    int qt2 = ot & 1, dt = ot >> 1;
    float inv = qt2 ? inv1 : inv0;
    int qg = qt2 * 32 + lq;
#pragma unroll
    for (int g = 0; g < 4; g++) {
      uint2 d;
      d.x = cvt_pk_bf16(oacc[ot][4 * g] * inv, oacc[ot][4 * g + 1] * inv);
      d.y = cvt_pk_bf16(oacc[ot][4 * g + 2] * inv, oacc[ot][4 * g + 3] * inv);
      *(uint2*)(lds + qg * 264 + w * 64 + dt * 32 + 8 * g + 4 * hi) = d;
    }
  }
  __syncthreads();
  short* obase = os + (((size_t)bb * 2048) + qb * 64) * 256;
#pragma unroll
  for (int rep = 0; rep < 8; rep++) {
    int cid = rep * 256 + tid;
    int row = cid >> 5, c = cid & 31;
    *(bf16x8*)(obase + row * 256 + c * 8) = *(const bf16x8*)(lds + row * 264 + c * 8);
  }
}

// ---- out = [O_L|O_H] @ w2^T + b_o : 64x128 tiles, BK=64, 1024 blocks, 3 blocks/CU ----
__launch_bounds__(256, 3)
__global__ void out_gemm(const short* __restrict__ os, const short* __restrict__ w2,
                         const float* __restrict__ bo, float* __restrict__ out) {
  __shared__ short alds[2][4096];   // 64 rows x 64 k (xor-chunk swizzled)
  __shared__ short blds[2][8192];   // 128 rows x 64 k
  int tid = threadIdx.x;
  int w = tid >> 6, L = tid & 63, lo = L & 15, hi = L >> 4;
  int wr = w >> 1, wc = w & 1;     // wave -> (32-row, 64-col) quadrant of 64x128
  int br = blockIdx.x, bc = blockIdx.y;

  // A DMA: 8 ops x 8 rows = 64 rows; op o = w*2+rep
  int arow[2], achk[2];
#pragma unroll
  for (int rep = 0; rep < 2; rep++) {
    int o = w * 2 + rep;
    int r = o * 8 + (L >> 3);
    arow[rep] = r;
    achk[rep] = ((L & 7) ^ (r & 7)) * 8;
  }
  // B DMA: 16 ops x 8 rows = 128 rows; op o = w*4+rep
  int brow[4], bchk[4];
#pragma unroll
  for (int rep = 0; rep < 4; rep++) {
    int o = w * 4 + rep;
    int r = o * 8 + (L >> 3);
    brow[rep] = r;
    bchk[rep] = ((L & 7) ^ (r & 7)) * 8;
  }
  int b = br >> 5;
  int s0 = (br & 31) * 64;
  const short* abase = os + ((size_t)(b * 2) * 2048 + s0) * 256;   // + half*2048*256 + row*256 + i0 + chk
  const short* bbase = w2 + (size_t)(bc * 128) * 512;              // + row*512 + kt*64 + chk

  f32x4 acc[2][4];
#pragma unroll
  for (int mt = 0; mt < 2; mt++)
#pragma unroll
    for (int nt = 0; nt < 4; nt++)
      acc[mt][nt] = (f32x4){0.f, 0.f, 0.f, 0.f};

  // frag read offsets (swizzle reduces to lo&7; rows multiple-of-16 apart)
  int fch[2];
#pragma unroll
  for (int kc = 0; kc < 2; kc++)
    fch[kc] = ((kc * 4 + hi) ^ (lo & 7)) * 8;

  // prologue: stage kt=0 into buf 0
#pragma unroll
  for (int rep = 0; rep < 2; rep++)
    async16(abase + arow[rep] * 256 + achk[rep], &alds[0][(w * 2 + rep) * 512] + L * 8);
#pragma unroll
  for (int rep = 0; rep < 4; rep++)
    async16(bbase + brow[rep] * 512 + bchk[rep], &blds[0][(w * 4 + rep) * 512] + L * 8);
  __syncthreads();

  int p = 0;
  for (int kt = 0; kt < 8; kt++) {
    if (kt < 7) {
      int k1 = kt + 1;
      int half = k1 >> 2, i0 = (k1 & 3) * 64;
      const short* ab = abase + (size_t)half * 2048 * 256 + i0;
#pragma unroll
      for (int rep = 0; rep < 2; rep++)
        async16(ab + arow[rep] * 256 + achk[rep], &alds[p ^ 1][(w * 2 + rep) * 512] + L * 8);
#pragma unroll
      for (int rep = 0; rep < 4; rep++)
        async16(bbase + brow[rep] * 512 + k1 * 64 + bchk[rep], &blds[p ^ 1][(w * 4 + rep) * 512] + L * 8);
    }
    bf16x8 af[2], bfr[4];
#pragma unroll
    for (int kc = 0; kc < 2; kc++) {
#pragma unroll
      for (int mt = 0; mt < 2; mt++)
        af[mt] = *(const bf16x8*)(&alds[p][(wr * 32 + mt * 16 + lo) * 64 + fch[kc]]);
#pragma unroll
      for (int nt = 0; nt < 4; nt++)
        bfr[nt] = *(const bf16x8*)(&blds[p][(wc * 64 + nt * 16 + lo) * 64 + fch[kc]]);
#pragma unroll
      for (int mt = 0; mt < 2; mt++)
#pragma unroll
        for (int nt = 0; nt < 4; nt++)
          acc[mt][nt] = __builtin_amdgcn_mfma_f32_16x16x32_bf16(af[mt], bfr[nt], acc[mt][nt], 0, 0, 0);
    }
    __syncthreads();   // reads of buf p done; DMA into p^1 drained
    p ^= 1;
  }

#pragma unroll
  for (int nt = 0; nt < 4; nt++) {
    int cc = bc * 128 + wc * 64 + nt * 16 + lo;
    float bias = bo[cc];
#pragma unroll
    for (int mt = 0; mt < 2; mt++) {
      int rrbase = br * 64 + wr * 32 + mt * 16 + hi * 4;
#pragma unroll
      for (int r = 0; r < 4; r++)
        out[(size_t)(rrbase + r) * 512 + cc] = acc[mt][nt][r] + bias;
    }
  }
}

extern "C" void kernel_launch(void* const* d_in, const int* in_sizes, int n_in,
                              void* d_out, int out_size, void* d_ws, size_t ws_size,
                              hipStream_t stream) {
  const float* q  = (const float*)d_in[0];
  const float* k  = (const float*)d_in[1];
  const float* v  = (const float*)d_in[2];
  const float* W  = (const float*)d_in[3];
  const float* bo = (const float*)d_in[4];
  short* ws  = (short*)d_ws;
  short* qs  = ws;
  short* ksb = ws + (size_t)8  * 1024 * 1024;
  short* vtp = ws + (size_t)16 * 1024 * 1024;
  short* osb = ws + (size_t)24 * 1024 * 1024;
  short* w2  = ws + (size_t)32 * 1024 * 1024;   // 512x512 bf16

  dwt_all<<<3200, 256, 0, stream>>>(q, k, v, W, qs, ksb, vtp, w2);
  flash_attn<<<dim3(16, 32), 256, 0, stream>>>(qs, ksb, vtp, osb);
  out_gemm<<<dim3(256, 4), 256, 0, stream>>>(osb, w2, bo, (float*)d_out);
}